// Round 18
// baseline (207.754 us; speedup 1.0000x reference)
//
#include <hip/hip_runtime.h>
#include <hip/hip_bf16.h>

// Fused Interaction Estimator, v18: v12 minus LDS A-staging.
// Inputs are L3-resident (201MB < 256MB; FETCH measured ~100MB), so A-tiles
// are loaded DIRECTLY from global inside the gemm (L1/L3-hot; the block's 4
// waves share lines via L1). Deletes: DMA staging, both vmcnt(0) HBM
// exposures (B0/B2 of v12), the XOR swizzle, and 16KB LDS. Barriers 5 -> 3
// (separate G/P stats arrays remove the WAR hazards). Sequential branches +
// 4-wave blocks retained (v15/v17 showed merging regresses).
// 6144 blocks x 256 threads, 16-row tiles, __launch_bounds__(256,4).

typedef float f32x4 __attribute__((ext_vector_type(4)));
typedef short short8 __attribute__((ext_vector_type(8)));
typedef unsigned int u32;

#define D_DIM 256
#define ROWS 16
#define NW 4

union S8 { short8 s; u32 u[4]; };

__device__ __forceinline__ u32 f2bfu(float x) {   // RNE f32->bf16 (finite)
  u32 u = __float_as_uint(x);
  return (u + 0x7FFFu + ((u >> 16) & 1u)) >> 16;
}
__device__ __forceinline__ float sigm(float x) { return 1.0f / (1.0f + __expf(-x)); }

__device__ __forceinline__ u32 pk2c(float a, float b) {   // -> v_cvt_pk_bf16_f32
  __hip_bfloat162 h = __float22bfloat162_rn(float2{a, b});
  union { __hip_bfloat162 h; u32 u; } cv;
  cv.h = h;
  return cv.u;
}

#define WAITL asm volatile("s_waitcnt lgkmcnt(0)" ::: "memory")

// ---------------- prep: pack W (f32 [k][m] row-major) into bf16 MFMA B-fragment order ----
// chunk = c*512 + t*64 + l holds 8 bf16: B[k = t*32 + (l>>4)*8 + j][m = c*16 + (l&15)]
__global__ __launch_bounds__(256) void pack_w_kernel(const float* __restrict__ Wg,
                                                     const float* __restrict__ Wp,
                                                     unsigned short* __restrict__ outp) {
  int b = blockIdx.x;
  const float* W = (b < 32) ? Wg : Wp;
  unsigned short* o = outp + (b < 32 ? 0 : 65536);
  int chunk = (b & 31) * 256 + threadIdx.x;
  int c = chunk >> 9;
  int rest = chunk & 511;
  int t = rest >> 6;
  int l = rest & 63;
  int m = c * 16 + (l & 15);
  int kb = t * 32 + ((l >> 4) << 3);
  short8 v;
#pragma unroll
  for (int j = 0; j < 8; ++j) v[j] = (short)f2bfu(W[(kb + j) * 256 + m]);
  *(short8*)(o + (size_t)chunk * 8) = v;
}

// ---------------- main fused kernel ----------------

__device__ __forceinline__ void barrier_fence() {
  __builtin_amdgcn_s_barrier();
  asm volatile("" ::: "memory");
}

// A-fragment (t) loaded DIRECTLY from global (f32, L1/L3-hot) -> bf16 frag.
// Same fragment semantics as v12's readAf32 (proven): row=cl, k = t*32+kg*8.
__device__ __forceinline__ short8 ldAg(const float* __restrict__ A, int t, int lane) {
  const int cl = lane & 15, kg = lane >> 4;
  const float* p = A + cl * D_DIM + kg * 8 + t * 32;
  float4 x = *(const float4*)p;
  float4 y = *(const float4*)(p + 4);
  S8 rr;
  rr.u[0] = pk2c(x.x, x.y);
  rr.u[1] = pk2c(x.z, x.w);
  rr.u[2] = pk2c(y.x, y.y);
  rr.u[3] = pk2c(y.z, y.w);
  return rr.s;
}

// batched gemm (v12-proven shape): per half, burst 4 A-frags (global) and per
// ct burst 4 B-frags (global, L2-hot). wave w owns cols w*64..+63.
__device__ __forceinline__ void gemm4(f32x4 acc[4], const float* __restrict__ A,
                                      const short8* __restrict__ wb, int lane, int w) {
  const int bbase = w * 2048 + lane;
#pragma unroll
  for (int h = 0; h < 2; ++h) {
    short8 a[4];
#pragma unroll
    for (int tt = 0; tt < 4; ++tt) a[tt] = ldAg(A, h * 4 + tt, lane);
#pragma unroll
    for (int c = 0; c < 4; ++c) {
      short8 bf[4];
#pragma unroll
      for (int tt = 0; tt < 4; ++tt) bf[tt] = wb[bbase + c * 512 + (h * 4 + tt) * 64];
#pragma unroll
      for (int tt = 0; tt < 4; ++tt)
        acc[c] = __builtin_amdgcn_mfma_f32_16x16x32_bf16(a[tt], bf[tt], acc[c], 0, 0, 0);
    }
  }
}

// bias + per-row (sum, sumsq) partials
__device__ __forceinline__ void statsPhase(f32x4 acc[4], const float bv[4],
                                           float smS[NW][ROWS], float smQ[NW][ROWS],
                                           int lane, int w) {
#pragma unroll
  for (int r = 0; r < 4; ++r) {
    float s = 0.f, qq = 0.f;
#pragma unroll
    for (int c = 0; c < 4; ++c) {
      float y = acc[c][r] + bv[c];
      acc[c][r] = y;
      s += y; qq += y * y;
    }
#pragma unroll
    for (int m = 1; m < 16; m <<= 1) {
      s += __shfl_xor(s, m, 64);
      qq += __shfl_xor(qq, m, 64);
    }
    if ((lane & 15) == 0) {
      int row = ((lane >> 4) << 2) + r;
      smS[w][row] = s;
      smQ[w][row] = qq;
    }
  }
}

__device__ __forceinline__ void applyPhase(f32x4 acc[4], f32x4 outAl[4],
                                           const float gv[4], const float tv[4], const float wv[4],
                                           const float smS[NW][ROWS], const float smQ[NW][ROWS],
                                           float smRed[NW][ROWS], int lane, int w) {
#pragma unroll
  for (int r = 0; r < 4; ++r) {
    int row = ((lane >> 4) << 2) + r;
    float s = 0.f, qq = 0.f;
#pragma unroll
    for (int k = 0; k < NW; ++k) { s += smS[k][row]; qq += smQ[k][row]; }
    float mu = s * (1.0f / 256.0f);
    float var = fmaxf(qq * (1.0f / 256.0f) - mu * mu, 0.0f);
    float rs = rsqrtf(var + 1e-5f);
    float dp = 0.f;
#pragma unroll
    for (int c = 0; c < 4; ++c) {
      float a = (acc[c][r] - mu) * rs * gv[c] + tv[c];
      a = fmaxf(a, 0.0f);
      outAl[c][r] = a;
      dp += a * wv[c];
    }
#pragma unroll
    for (int m = 1; m < 16; m <<= 1) dp += __shfl_xor(dp, m, 64);
    if ((lane & 15) == 0) smRed[w][row] = dp;
  }
}

__global__ __launch_bounds__(256, 4) void fused_main(
    const float* __restrict__ gfeat, const float* __restrict__ pfeat,
    const float* __restrict__ bg, const float* __restrict__ glng, const float* __restrict__ glnb,
    const float* __restrict__ bp, const float* __restrict__ plng, const float* __restrict__ plnb,
    const float* __restrict__ wag, const float* __restrict__ bag,
    const float* __restrict__ wap, const float* __restrict__ bap,
    const unsigned short* __restrict__ wpk,
    float* __restrict__ outp)
{
  // LDS: only the 6 tiny partial arrays (6 KB total) -- no A buffer.
  __shared__ float smSG[NW][ROWS], smQG[NW][ROWS];
  __shared__ float smSP[NW][ROWS], smQP[NW][ROWS];
  __shared__ float smRG[NW][ROWS], smRP[NW][ROWS];

  const int tid = threadIdx.x;
  const int lane = tid & 63;
  const int w = tid >> 6;
  const size_t row0 = (size_t)blockIdx.x * ROWS;

  const short8* wbg = (const short8*)wpk;
  const short8* wbp = (const short8*)(wpk + 65536);
  const float* Ag = gfeat + row0 * D_DIM;
  const float* Ap = pfeat + row0 * D_DIM;

  // param hoist (no DMAs exist to be drained by these)
  const int cb = w * 64 + (lane & 15);
  float bvG[4], bvP[4];
#pragma unroll
  for (int c = 0; c < 4; ++c) {
    bvG[c] = bg[cb + c * 16];
    bvP[c] = bp[cb + c * 16];
  }
  const float vbag = bag[0], vbap = bap[0];

  // ---- g branch ----
  f32x4 accG[4];
#pragma unroll
  for (int c = 0; c < 4; ++c) accG[c] = {0.f, 0.f, 0.f, 0.f};
  gemm4(accG, Ag, wbg, lane, w);
  statsPhase(accG, bvG, smSG, smQG, lane, w);
  WAITL;
  barrier_fence();                       // B1: statsG partials visible

  float gvG[4], tvG[4], wvG[4], gvP[4], tvP[4], wvP[4];
#pragma unroll
  for (int c = 0; c < 4; ++c) {
    gvG[c] = glng[cb + c * 16];
    tvG[c] = glnb[cb + c * 16];
    wvG[c] = wap[cb + c * 16];    // g_align . wa_p
    gvP[c] = plng[cb + c * 16];
    tvP[c] = plnb[cb + c * 16];
    wvP[c] = wag[cb + c * 16];    // p_align . wa_g
  }

  f32x4 alignG[4];
  applyPhase(accG, alignG, gvG, tvG, wvG, smSG, smQG, smRG, lane, w);

  // ---- p branch (separate stats arrays: no WAR with applyG's smSG reads) ----
  f32x4 accP[4];
#pragma unroll
  for (int c = 0; c < 4; ++c) accP[c] = {0.f, 0.f, 0.f, 0.f};
  gemm4(accP, Ap, wbp, lane, w);
  statsPhase(accP, bvP, smSP, smQP, lane, w);
  WAITL;
  barrier_fence();                       // B2: statsP partials visible (smRG also visible)

  applyPhase(accP, accP, gvP, tvP, wvP, smSP, smQP, smRP, lane, w);  // acc := alignP
  WAITL;
  barrier_fence();                       // B3: smRP visible

  // ---- fusion + store ----
#pragma unroll
  for (int r = 0; r < 4; ++r) {
    int row = ((lane >> 4) << 2) + r;
    float gr = 0.f, pr = 0.f;
#pragma unroll
    for (int k = 0; k < NW; ++k) { gr += smRG[k][row]; pr += smRP[k][row]; }
    float* orow = outp + (row0 + row) * D_DIM + w * 64 + (lane & 15);
#pragma unroll
    for (int c = 0; c < 4; ++c) {
      float ga = alignG[c][r];
      float pa = accP[c][r];
      float geno = sigm(ga * pr + vbag);
      float path = sigm(pa * gr + vbap);
      orow[c * 16] = pa * path + ga * geno;
    }
  }
}

extern "C" void kernel_launch(void* const* d_in, const int* in_sizes, int n_in,
                              void* d_out, int out_size, void* d_ws, size_t ws_size,
                              hipStream_t stream) {
  const float* gfeat = (const float*)d_in[0];
  const float* pfeat = (const float*)d_in[1];
  const float* Wg   = (const float*)d_in[2];
  const float* bg   = (const float*)d_in[3];
  const float* glng = (const float*)d_in[4];
  const float* glnb = (const float*)d_in[5];
  const float* Wp   = (const float*)d_in[6];
  const float* bp   = (const float*)d_in[7];
  const float* plng = (const float*)d_in[8];
  const float* plnb = (const float*)d_in[9];
  const float* wag  = (const float*)d_in[10];
  const float* bag  = (const float*)d_in[11];
  const float* wap  = (const float*)d_in[12];
  const float* bap  = (const float*)d_in[13];
  float* outp = (float*)d_out;
  unsigned short* wpk = (unsigned short*)d_ws;   // 256 KB used

  hipLaunchKernelGGL(pack_w_kernel, dim3(64), dim3(256), 0, stream, Wg, Wp, wpk);

  int nrows = in_sizes[0] / D_DIM;   // 98304
  int nblocks = nrows / ROWS;        // 6144
  hipLaunchKernelGGL(fused_main, dim3(nblocks), dim3(256), 0, stream,
                     gfeat, pfeat, bg, glng, glnb, bp, plng, plnb,
                     wag, bag, wap, bap, wpk, outp);
}

// Round 19
// 121.783 us; speedup vs baseline: 1.7059x; 1.7059x over previous
//
#include <hip/hip_runtime.h>
#include <hip/hip_bf16.h>

// Fused Interaction Estimator, v19: v12 (128us champion) with ONE change:
// all 16-lane __shfl_xor reductions (ds_swizzle -> LDS pipe, ~40-60cy each,
// 4-deep serial chains) replaced by pure-VALU DPP butterflies:
//   quad_perm[1,0,3,2] (xor1), quad_perm[2,3,0,1] (xor2),
//   row_half_mirror (8-group), row_mirror (16-group)
// => ~96 LDS-pipe ops/thread removed, reduction chains ~10x shorter, and the
// LDS pipe is freed for the A-buffer ds_reads. Everything else identical to
// v12: 6144 blocks x 256 threads, 16-row tiles, single 16KB f32 A-buffer
// (g then p), source-XOR-swizzled global_load_lds, counted s_waitcnt + raw
// s_barrier, batched gemm, in-gemm f32->bf16 cvt_pk.

typedef float f32x4 __attribute__((ext_vector_type(4)));
typedef short short8 __attribute__((ext_vector_type(8)));
typedef unsigned int u32;

#define D_DIM 256
#define ROWS 16
#define NW 4

union S8 { short8 s; u32 u[4]; };

__device__ __forceinline__ u32 f2bfu(float x) {   // RNE f32->bf16 (finite)
  u32 u = __float_as_uint(x);
  return (u + 0x7FFFu + ((u >> 16) & 1u)) >> 16;
}
__device__ __forceinline__ float sigm(float x) { return 1.0f / (1.0f + __expf(-x)); }

__device__ __forceinline__ u32 pk2c(float a, float b) {   // -> v_cvt_pk_bf16_f32
  __hip_bfloat162 h = __float22bfloat162_rn(float2{a, b});
  union { __hip_bfloat162 h; u32 u; } cv;
  cv.h = h;
  return cv.u;
}

// 16-lane butterfly sum, pure VALU (DPP): after 4 steps every lane in each
// 16-lane group holds the group sum. quad_perm xor1=0xB1, xor2=0x4E;
// row_half_mirror=0x141, row_mirror=0x140.
__device__ __forceinline__ float dpp_sum16(float x) {
  float s = x;
  s += __int_as_float(__builtin_amdgcn_update_dpp(0, __float_as_int(s), 0xB1, 0xF, 0xF, true));
  s += __int_as_float(__builtin_amdgcn_update_dpp(0, __float_as_int(s), 0x4E, 0xF, 0xF, true));
  s += __int_as_float(__builtin_amdgcn_update_dpp(0, __float_as_int(s), 0x141, 0xF, 0xF, true));
  s += __int_as_float(__builtin_amdgcn_update_dpp(0, __float_as_int(s), 0x140, 0xF, 0xF, true));
  return s;
}

// ---------------- prep: pack W (f32 [k][m] row-major) into bf16 MFMA B-fragment order ----
// chunk = c*512 + t*64 + l holds 8 bf16: B[k = t*32 + (l>>4)*8 + j][m = c*16 + (l&15)]
__global__ __launch_bounds__(256) void pack_w_kernel(const float* __restrict__ Wg,
                                                     const float* __restrict__ Wp,
                                                     unsigned short* __restrict__ outp) {
  int b = blockIdx.x;
  const float* W = (b < 32) ? Wg : Wp;
  unsigned short* o = outp + (b < 32 ? 0 : 65536);
  int chunk = (b & 31) * 256 + threadIdx.x;
  int c = chunk >> 9;
  int rest = chunk & 511;
  int t = rest >> 6;
  int l = rest & 63;
  int m = c * 16 + (l & 15);
  int kb = t * 32 + ((l >> 4) << 3);
  short8 v;
#pragma unroll
  for (int j = 0; j < 8; ++j) v[j] = (short)f2bfu(W[(kb + j) * 256 + m]);
  *(short8*)(o + (size_t)chunk * 8) = v;
}

// ---------------- main fused kernel ----------------

// issue 4 row-DMAs for wave w into lbuf (f32, source-swizzled at 16B granules)
__device__ __forceinline__ void stage_dma(const float* __restrict__ src, float* lbuf,
                                          int w, int lane) {
#pragma unroll
  for (int j = 0; j < 4; ++j) {
    int r = w * 4 + j;
    const float* gp = src + r * D_DIM + ((lane ^ (r & 7)) << 2);   // 16B granule XOR
    float* lp = lbuf + r * D_DIM;                                  // wave-uniform, linear
    __builtin_amdgcn_global_load_lds(
        (const __attribute__((address_space(1))) u32*)gp,
        (__attribute__((address_space(3))) u32*)lp, 16, 0, 0);
  }
}

__device__ __forceinline__ void barrier_fence() {
  __builtin_amdgcn_s_barrier();
  asm volatile("" ::: "memory");
}

// read A-fragment (t) from swizzled f32 LDS tile and convert to bf16
__device__ __forceinline__ short8 readAf32(const float* buf, int t, int lane) {
  const int cl = lane & 15, kg = lane >> 4;
  const int r = cl;                 // 16-row tile: row == cl
  const int s = r & 7;
  const int c16 = t * 8 + kg * 2;   // 16B-granule index within the row
  const char* base = (const char*)buf + r * 1024;
  float4 x = *(const float4*)(base + ((c16 ^ s) << 4));
  float4 y = *(const float4*)(base + (((c16 + 1) ^ s) << 4));
  S8 rr;
  rr.u[0] = pk2c(x.x, x.y);
  rr.u[1] = pk2c(x.z, x.w);
  rr.u[2] = pk2c(y.x, y.y);
  rr.u[3] = pk2c(y.z, y.w);
  return rr.s;
}

// batched gemm: per half, burst-read 4 A-frags; per ct, burst-load 4 B-frags.
// wave w owns cols w*64 .. w*64+63 (ct = w*4 + c)
__device__ __forceinline__ void gemm4(f32x4 acc[4], const float* buf,
                                      const short8* __restrict__ wb, int lane, int w) {
  const int bbase = w * 2048 + lane;
#pragma unroll
  for (int h = 0; h < 2; ++h) {
    short8 a[4];
#pragma unroll
    for (int tt = 0; tt < 4; ++tt) a[tt] = readAf32(buf, h * 4 + tt, lane);
#pragma unroll
    for (int c = 0; c < 4; ++c) {
      short8 bf[4];
#pragma unroll
      for (int tt = 0; tt < 4; ++tt) bf[tt] = wb[bbase + c * 512 + (h * 4 + tt) * 64];
#pragma unroll
      for (int tt = 0; tt < 4; ++tt)
        acc[c] = __builtin_amdgcn_mfma_f32_16x16x32_bf16(a[tt], bf[tt], acc[c], 0, 0, 0);
    }
  }
}

// bias + per-row (sum, sumsq) partials -- DPP butterflies, no LDS-pipe ops
__device__ __forceinline__ void statsPhase(f32x4 acc[4], const float* __restrict__ bias,
                                           float smSum[NW][ROWS], float smSq[NW][ROWS],
                                           int lane, int w) {
  float bv[4];
#pragma unroll
  for (int c = 0; c < 4; ++c) bv[c] = bias[w * 64 + c * 16 + (lane & 15)];
#pragma unroll
  for (int r = 0; r < 4; ++r) {
    float s = 0.f, qq = 0.f;
#pragma unroll
    for (int c = 0; c < 4; ++c) {
      float y = acc[c][r] + bv[c];
      acc[c][r] = y;
      s += y; qq += y * y;
    }
    s = dpp_sum16(s);
    qq = dpp_sum16(qq);
    if ((lane & 15) == 0) {
      int row = ((lane >> 4) << 2) + r;
      smSum[w][row] = s;
      smSq[w][row] = qq;
    }
  }
}

__device__ __forceinline__ void applyPhase(f32x4 acc[4], f32x4 outAl[4],
                                           const float* __restrict__ gam, const float* __restrict__ bet,
                                           const float* __restrict__ wa,
                                           const float smSum[NW][ROWS], const float smSq[NW][ROWS],
                                           float smRed[NW][ROWS], int lane, int w) {
  int cb = w * 64 + (lane & 15);
  float gv[4], tv[4], wv[4];
#pragma unroll
  for (int c = 0; c < 4; ++c) {
    gv[c] = gam[cb + c * 16];
    tv[c] = bet[cb + c * 16];
    wv[c] = wa[cb + c * 16];
  }
#pragma unroll
  for (int r = 0; r < 4; ++r) {
    int row = ((lane >> 4) << 2) + r;
    float s = 0.f, qq = 0.f;
#pragma unroll
    for (int k = 0; k < NW; ++k) { s += smSum[k][row]; qq += smSq[k][row]; }
    float mu = s * (1.0f / 256.0f);
    float var = fmaxf(qq * (1.0f / 256.0f) - mu * mu, 0.0f);
    float rs = rsqrtf(var + 1e-5f);
    float dp = 0.f;
#pragma unroll
    for (int c = 0; c < 4; ++c) {
      float a = (acc[c][r] - mu) * rs * gv[c] + tv[c];
      a = fmaxf(a, 0.0f);
      outAl[c][r] = a;
      dp += a * wv[c];
    }
    dp = dpp_sum16(dp);
    if ((lane & 15) == 0) smRed[w][row] = dp;
  }
}

__global__ __launch_bounds__(256, 4) void fused_main(
    const float* __restrict__ gfeat, const float* __restrict__ pfeat,
    const float* __restrict__ bg, const float* __restrict__ glng, const float* __restrict__ glnb,
    const float* __restrict__ bp, const float* __restrict__ plng, const float* __restrict__ plnb,
    const float* __restrict__ wag, const float* __restrict__ bag,
    const float* __restrict__ wap, const float* __restrict__ bap,
    const unsigned short* __restrict__ wpk,
    float* __restrict__ outp)
{
  __shared__ float bufA[ROWS * D_DIM];   // 16 KB raw f32, source-swizzled; g then p
  __shared__ float smSum[NW][ROWS], smSq[NW][ROWS], smRedG[NW][ROWS], smRedP[NW][ROWS];

  const int tid = threadIdx.x;
  const int lane = tid & 63;
  const int w = tid >> 6;
  const size_t row0 = (size_t)blockIdx.x * ROWS;

  const short8* wbg = (const short8*)wpk;
  const short8* wbp = (const short8*)(wpk + 65536);

  // stage g tile (4 DMAs/wave, zero VGPR)
  stage_dma(gfeat + row0 * D_DIM, bufA, w, lane);
  asm volatile("s_waitcnt vmcnt(0)" ::: "memory");
  barrier_fence();                       // B0: g staged

  f32x4 accG[4];
#pragma unroll
  for (int c = 0; c < 4; ++c) accG[c] = {0.f, 0.f, 0.f, 0.f};
  gemm4(accG, bufA, wbg, lane, w);
  statsPhase(accG, bg, smSum, smSq, lane, w);
  asm volatile("s_waitcnt lgkmcnt(0)" ::: "memory");
  barrier_fence();                       // B1: statsG visible; all g-reads of bufA done

  // p tile into the SAME buffer; latency covered by applyG + other resident blocks
  stage_dma(pfeat + row0 * D_DIM, bufA, w, lane);

  f32x4 alignG[4];
  applyPhase(accG, alignG, glng, glnb, wap, smSum, smSq, smRedG, lane, w);
  asm volatile("s_waitcnt vmcnt(0) lgkmcnt(0)" ::: "memory");
  barrier_fence();                       // B2: p staged; smRedG visible; applyG smSum reads done

  f32x4 accP[4];
#pragma unroll
  for (int c = 0; c < 4; ++c) accP[c] = {0.f, 0.f, 0.f, 0.f};
  gemm4(accP, bufA, wbp, lane, w);
  statsPhase(accP, bp, smSum, smSq, lane, w);   // smSum rewrite: applyG reads ended at B2
  asm volatile("s_waitcnt lgkmcnt(0)" ::: "memory");
  barrier_fence();                       // B3: statsP visible

  applyPhase(accP, accP, plng, plnb, wag, smSum, smSq, smRedP, lane, w);  // acc := alignP
  asm volatile("s_waitcnt lgkmcnt(0)" ::: "memory");
  barrier_fence();                       // B4: smRedP visible

  // fusion + store
  const float vbag = bag[0], vbap = bap[0];
#pragma unroll
  for (int r = 0; r < 4; ++r) {
    int row = ((lane >> 4) << 2) + r;
    float gr = 0.f, pr = 0.f;
#pragma unroll
    for (int k = 0; k < NW; ++k) { gr += smRedG[k][row]; pr += smRedP[k][row]; }
    float* orow = outp + (row0 + row) * D_DIM + w * 64 + (lane & 15);
#pragma unroll
    for (int c = 0; c < 4; ++c) {
      float ga = alignG[c][r];
      float pa = accP[c][r];
      float geno = sigm(ga * pr + vbag);
      float path = sigm(pa * gr + vbap);
      orow[c * 16] = pa * path + ga * geno;
    }
  }
}

extern "C" void kernel_launch(void* const* d_in, const int* in_sizes, int n_in,
                              void* d_out, int out_size, void* d_ws, size_t ws_size,
                              hipStream_t stream) {
  const float* gfeat = (const float*)d_in[0];
  const float* pfeat = (const float*)d_in[1];
  const float* Wg   = (const float*)d_in[2];
  const float* bg   = (const float*)d_in[3];
  const float* glng = (const float*)d_in[4];
  const float* glnb = (const float*)d_in[5];
  const float* Wp   = (const float*)d_in[6];
  const float* bp   = (const float*)d_in[7];
  const float* plng = (const float*)d_in[8];
  const float* plnb = (const float*)d_in[9];
  const float* wag  = (const float*)d_in[10];
  const float* bag  = (const float*)d_in[11];
  const float* wap  = (const float*)d_in[12];
  const float* bap  = (const float*)d_in[13];
  float* outp = (float*)d_out;
  unsigned short* wpk = (unsigned short*)d_ws;   // 256 KB used

  hipLaunchKernelGGL(pack_w_kernel, dim3(64), dim3(256), 0, stream, Wg, Wp, wpk);

  int nrows = in_sizes[0] / D_DIM;   // 98304
  int nblocks = nrows / ROWS;        // 6144
  hipLaunchKernelGGL(fused_main, dim3(nblocks), dim3(256), 0, stream,
                     gfeat, pfeat, bg, glng, glnb, bp, plng, plnb,
                     wag, bag, wap, bap, wpk, outp);
}